// Round 8
// baseline (147.609 us; speedup 1.0000x reference)
//
#include <hip/hip_runtime.h>

// EndEffectorLoss: rot6d -> R, FK over fixed 24-joint tree, end-effector MSE.
// R8 = R7 (wave-private LDS, frame-transposed coalesced loads) restructured
// into 3 stages of 8 joints with an EXPLICIT register-buffered software
// pipeline: stage k+1's 18 float4 loads are issued before FK(k) compute, so
// L3 latency (~600cy) hides under ~800cy of FK. R7's counters showed ~84k
// stalled cycles/wave = serially-exposed load clusters; this removes all but
// the first. LDS 75.9KB -> 2 blocks/CU (grid 512 = all frames); ee-exchange
// aliases the dead pose buffer. No VGPR cap: need only 2 waves/SIMD.

struct V3 { float x, y, z; };
struct M3 { float m[3][3]; };   // row r = basis vector b_r (row-stacked)

__device__ __forceinline__ V3 matvec(const M3& A, const V3& v) {
    return { A.m[0][0]*v.x + A.m[0][1]*v.y + A.m[0][2]*v.z,
             A.m[1][0]*v.x + A.m[1][1]*v.y + A.m[1][2]*v.z,
             A.m[2][0]*v.x + A.m[2][1]*v.y + A.m[2][2]*v.z };
}

__device__ __forceinline__ M3 matmul(const M3& A, const M3& B) {
    M3 C;
#pragma unroll
    for (int i = 0; i < 3; i++)
#pragma unroll
        for (int j = 0; j < 3; j++)
            C.m[i][j] = A.m[i][0]*B.m[0][j] + A.m[i][1]*B.m[1][j] + A.m[i][2]*B.m[2][j];
    return C;
}

#define PROW 49   // 48 pose words/stage + 1 pad (49 coprime 32)
#define OROW 25   // 24 off words/stage + 1 pad (25 coprime 32)

struct FK { M3 o; V3 p; };

__device__ __forceinline__ M3 rot6d_lds(const float* __restrict__ rp, int base) {
    float v0 = rp[base+0], v1 = rp[base+1], v2 = rp[base+2];
    float v3 = rp[base+3], v4 = rp[base+4], v5 = rp[base+5];
    float n1 = v0*v0 + v1*v1 + v2*v2;
    float r1 = 1.0f / sqrtf(n1);
    V3 b1 = { v0*r1, v1*r1, v2*r1 };
    float d = b1.x*v3 + b1.y*v4 + b1.z*v5;
    V3 u = { v3 - d*b1.x, v4 - d*b1.y, v5 - d*b1.z };
    float n2 = u.x*u.x + u.y*u.y + u.z*u.z;
    float r2 = 1.0f / sqrtf(n2);
    V3 b2 = { u.x*r2, u.y*r2, u.z*r2 };
    V3 b3 = { b1.y*b2.z - b1.z*b2.y, b1.z*b2.x - b1.x*b2.z, b1.x*b2.y - b1.y*b2.x };
    M3 R;
    R.m[0][0]=b1.x; R.m[0][1]=b1.y; R.m[0][2]=b1.z;
    R.m[1][0]=b2.x; R.m[1][1]=b2.y; R.m[1][2]=b2.z;
    R.m[2][0]=b3.x; R.m[2][1]=b3.y; R.m[2][2]=b3.z;
    return R;
}

__device__ __forceinline__ FK fk_step_l(const float* __restrict__ rp,
                                        const float* __restrict__ ro,
                                        int pb, int ob, const FK& par) {
    V3 off = { ro[ob], ro[ob+1], ro[ob+2] };
    V3 t = matvec(par.o, off);
    FK s;
    s.p = { par.p.x + t.x, par.p.y + t.y, par.p.z + t.z };
    s.o = matmul(par.o, rot6d_lds(rp, pb));
    return s;
}

__device__ __forceinline__ V3 fk_end_l(const float* __restrict__ ro,
                                       int ob, const FK& par) {
    V3 off = { ro[ob], ro[ob+1], ro[ob+2] };
    V3 t = matvec(par.o, off);
    return { par.p.x + t.x, par.p.y + t.y, par.p.z + t.z };
}

__global__ __launch_bounds__(256)
void ee_loss_kernel(const float* __restrict__ poseA, const float* __restrict__ poseB,
                    const float* __restrict__ offA,  const float* __restrict__ offB,
                    const float* __restrict__ tA,    const float* __restrict__ tB,
                    float* __restrict__ out, float inv_count) {
    __shared__ float s_pose[4][64 * PROW];   // 50.2 KB, wave-private slices
    __shared__ float s_off [4][64 * OROW];   // 25.6 KB
    __shared__ float s_inv[6];
    __shared__ float s_d[15];
    __shared__ float s_part[2];

    const int tid  = threadIdx.x;
    const int wid  = tid >> 6;            // 0..3
    const int lane = tid & 63;
    const bool isB = wid & 1;             // waves 1,3 -> pose B
    const int fg   = wid >> 1;            // frame-group 0/1
    const int fl   = fg * 64 + lane;      // 0..127
    const long long f0 = (long long)blockIdx.x * 128 + fg * 64;

    const float* __restrict__ P = (isB ? poseB : poseA) + f0 * 144;
    const float* __restrict__ O = (isB ? offB  : offA ) + f0 * 72;

    float* sp = s_pose[wid];
    float* so = s_off[wid];
    const float* rp = sp + lane * PROW;
    const float* ro = so + lane * OROW;

    // ---- t_pose-derived constants ----
    if (tid < 6) {
        const float* tp = (tid < 3) ? tA : tB;
        int ax = (tid < 3) ? tid : tid - 3;
        float mn = tp[ax], mx = mn;
#pragma unroll
        for (int j = 1; j < 24; j++) {
            float v = tp[j*3 + ax];
            mn = fminf(mn, v); mx = fmaxf(mx, v);
        }
        s_inv[tid] = 1.0f / (mx - mn);
    }
    if (tid < 15) {
        const int EE[5] = {10, 11, 15, 22, 23};
        int e = tid / 3, ax = tid - 3*e;
        int j = EE[e];
        float mnA = tA[ax], mxA = mnA, mnB = tB[ax], mxB = mnB;
#pragma unroll
        for (int k = 1; k < 24; k++) {
            float a = tA[k*3 + ax], b = tB[k*3 + ax];
            mnA = fminf(mnA, a); mxA = fmaxf(mxA, a);
            mnB = fminf(mnB, b); mxB = fmaxf(mxB, b);
        }
        s_d[tid] = tB[j*3 + ax]/(mxB - mnB) - tA[j*3 + ax]/(mxA - mnA);
    }

    // ---- staging helpers (wave-private; no barriers) ----
    // pose stage st: 64 frames x 48 words = 768 f32 = 192 float4; 12/lane.
    // off  stage st: 64 frames x 24 words = 384 f32 = 96 float4; 6/lane.
    // All global addrs 16B-aligned: 576f + 192st + 16c / 288f + 96st + 16c.
    auto gload = [&](float4* cp, float4* co, int st) {
#pragma unroll
        for (int k = 0; k < 12; k++) {
            int idx = lane + 64 * k;
            int f = idx / 12, c = idx - 12 * f;
            cp[k] = *(const float4*)(P + f*144 + st*48 + c*4);
        }
#pragma unroll
        for (int k = 0; k < 6; k++) {
            int idx = lane + 64 * k;
            int f = idx / 6, c = idx - 6 * f;
            co[k] = *(const float4*)(O + f*72 + st*24 + c*4);
        }
    };
    auto swrite = [&](const float4* cp, const float4* co) {
#pragma unroll
        for (int k = 0; k < 12; k++) {
            int idx = lane + 64 * k;
            int f = idx / 12, c = idx - 12 * f;
            float* d = sp + f*PROW + c*4;
            d[0] = cp[k].x; d[1] = cp[k].y; d[2] = cp[k].z; d[3] = cp[k].w;
        }
#pragma unroll
        for (int k = 0; k < 6; k++) {
            int idx = lane + 64 * k;
            int f = idx / 6, c = idx - 6 * f;
            float* d = so + f*OROW + c*4;
            d[0] = co[k].x; d[1] = co[k].y; d[2] = co[k].z; d[3] = co[k].w;
        }
    };

    float4 cpA[12], coA[6];     // pipeline slot A
    float4 cpB[12], coB[6];     // pipeline slot B

    // ---- software pipeline: S0 in A, S1 in B, S2 reuses A ----
    gload(cpA, coA, 0);                  // exposed once
    gload(cpB, coB, 1);                  // in flight under FK(S0)
    __builtin_amdgcn_sched_barrier(0);   // pin prefetch above everything below
    swrite(cpA, coA);                    // waits vmcnt for slot A only

    // FK stage 0: joints 0..7 (stage-local base = j*6 / j*3)
    FK s0; s0.o = rot6d_lds(rp, 0); s0.p = { ro[0], ro[1], ro[2] };
    FK s1 = fk_step_l(rp, ro,  6,  3, s0);
    FK s2 = fk_step_l(rp, ro, 12,  6, s0);
    FK s3 = fk_step_l(rp, ro, 18,  9, s0);
    FK s4 = fk_step_l(rp, ro, 24, 12, s1);
    FK s5 = fk_step_l(rp, ro, 30, 15, s2);
    FK s6 = fk_step_l(rp, ro, 36, 18, s3);
    FK s7 = fk_step_l(rp, ro, 42, 21, s4);

    swrite(cpB, coB);                    // after FK(S0) reads (program order)
    gload(cpA, coA, 2);                  // in flight under FK(S1)
    __builtin_amdgcn_sched_barrier(0);

    // FK stage 1: joints 8..15 (local j-8); 10,11,15 end sites
    FK s8  = fk_step_l(rp, ro,  0,  0, s5);
    FK s9  = fk_step_l(rp, ro,  6,  3, s6);
    V3 e10 = fk_end_l(ro,  6, s7);
    V3 e11 = fk_end_l(ro,  9, s8);
    FK s12 = fk_step_l(rp, ro, 24, 12, s9);
    FK s13 = fk_step_l(rp, ro, 30, 15, s9);
    FK s14 = fk_step_l(rp, ro, 36, 18, s9);
    V3 e15 = fk_end_l(ro, 21, s12);

    swrite(cpA, coA);                    // after FK(S1) reads

    // FK stage 2: joints 16..23 (local j-16); 22,23 end sites
    FK s16 = fk_step_l(rp, ro,  0,  0, s13);
    FK s17 = fk_step_l(rp, ro,  6,  3, s14);
    FK s18 = fk_step_l(rp, ro, 12,  6, s16);
    FK s19 = fk_step_l(rp, ro, 18,  9, s17);
    FK s20 = fk_step_l(rp, ro, 24, 12, s18);
    FK s21 = fk_step_l(rp, ro, 30, 15, s19);
    V3 e22 = fk_end_l(ro, 18, s20);
    V3 e23 = fk_end_l(ro, 21, s21);

    // ---- exchange: alias ee buffer onto dead pose LDS (saves 7.7KB) ----
    float (*s_eeB)[15] = (float (*)[15])(&s_pose[0][0]);   // 1920 floats
    __syncthreads();                     // all FK LDS reads done everywhere
    if (isB) {
        s_eeB[fl][ 0] = e10.x; s_eeB[fl][ 1] = e10.y; s_eeB[fl][ 2] = e10.z;
        s_eeB[fl][ 3] = e11.x; s_eeB[fl][ 4] = e11.y; s_eeB[fl][ 5] = e11.z;
        s_eeB[fl][ 6] = e15.x; s_eeB[fl][ 7] = e15.y; s_eeB[fl][ 8] = e15.z;
        s_eeB[fl][ 9] = e22.x; s_eeB[fl][10] = e22.y; s_eeB[fl][11] = e22.z;
        s_eeB[fl][12] = e23.x; s_eeB[fl][13] = e23.y; s_eeB[fl][14] = e23.z;
    }
    __syncthreads();

    float local = 0.0f;
    if (!isB) {
        const float iax = s_inv[0], iay = s_inv[1], iaz = s_inv[2];
        const float ibx = s_inv[3], iby = s_inv[4], ibz = s_inv[5];
        const float* eb = s_eeB[fl];
        float t0  = e10.x*iax - eb[ 0]*ibx + s_d[ 0];
        float t1  = e10.y*iay - eb[ 1]*iby + s_d[ 1];
        float t2  = e10.z*iaz - eb[ 2]*ibz + s_d[ 2];
        float t3  = e11.x*iax - eb[ 3]*ibx + s_d[ 3];
        float t4  = e11.y*iay - eb[ 4]*iby + s_d[ 4];
        float t5  = e11.z*iaz - eb[ 5]*ibz + s_d[ 5];
        float t6  = e15.x*iax - eb[ 6]*ibx + s_d[ 6];
        float t7  = e15.y*iay - eb[ 7]*iby + s_d[ 7];
        float t8  = e15.z*iaz - eb[ 8]*ibz + s_d[ 8];
        float t9  = e22.x*iax - eb[ 9]*ibx + s_d[ 9];
        float t10 = e22.y*iay - eb[10]*iby + s_d[10];
        float t11 = e22.z*iaz - eb[11]*ibz + s_d[11];
        float t12 = e23.x*iax - eb[12]*ibx + s_d[12];
        float t13 = e23.y*iay - eb[13]*iby + s_d[13];
        float t14 = e23.z*iaz - eb[14]*ibz + s_d[14];
        local = ((t0*t0 + t1*t1) + (t2*t2 + t3*t3) + (t4*t4 + t5*t5) +
                 (t6*t6 + t7*t7) + (t8*t8 + t9*t9) + (t10*t10 + t11*t11) +
                 (t12*t12 + t13*t13) + t14*t14) * inv_count;
#pragma unroll
        for (int off = 32; off > 0; off >>= 1)
            local += __shfl_down(local, off, 64);
        if (lane == 0) s_part[fg] = local;
    }
    __syncthreads();
    if (tid == 0) atomicAdd(out, s_part[0] + s_part[1]);
}

extern "C" void kernel_launch(void* const* d_in, const int* in_sizes, int n_in,
                              void* d_out, int out_size, void* d_ws, size_t ws_size,
                              hipStream_t stream) {
    const float* poseA = (const float*)d_in[0];
    const float* poseB = (const float*)d_in[1];
    const float* offA  = (const float*)d_in[2];
    const float* offB  = (const float*)d_in[3];
    const float* tA    = (const float*)d_in[4];
    const float* tB    = (const float*)d_in[5];
    float* out = (float*)d_out;

    const int F = in_sizes[0] / 144;          // 65536
    const int blocks = F / 128;               // 512
    const float inv_count = 1.0f / ((float)F * 15.0f);

    hipMemsetAsync(out, 0, sizeof(float), stream);
    ee_loss_kernel<<<blocks, 256, 0, stream>>>(poseA, poseB, offA, offB, tA, tB,
                                               out, inv_count);
}